// Round 9
// baseline (268.870 us; speedup 1.0000x reference)
//
#include <hip/hip_runtime.h>

// ZBL screened repulsion + sorted segment sum.
//   d_in[0] Z int32[500000], d_in[1] Dij fp32[16e6], d_in[2] idx_i int32[16e6] (sorted),
//   d_in[3] idx_j int32[16e6], d_in[4] p, d_in[5] d, d_in[6] c[4], d_in[7] a[4]
// Output: fp32[500000] segment_sum over idx_i.
//
// Round 9: model from R2-R8: gather cost = ~4.6-5.6 cyc per L1-MISSING lane
// (TCP miss path), invariant to occupancy / cache level / address dedup;
// L1-hit lanes free. 16M miss-lanes -> 120us floor == measured R5/R6 121us.
// Last lever: make in-slice lanes generate NO request. R7's branches killed
// MLP; R8's address-redirect kept all lanes on the miss path. This round
// uses BUFFER loads with OOB voffset for in-slice lanes: SRD bounds check
// drops OOB lanes at the TA (no request, returns 0) while the instruction
// issues unconditionally -> branch-free, if-conversion-proof, MLP=16.
// In-slice (29.5%, 144KB LDS byte-slice) served by ds_read.

#define EPT    16        // edges per thread (16e6 divisible by 16)
#define BLOCK  1024
#define MAXZ   96
#define SL     147456    // atoms cached in LDS (144KB of bytes)

#define HAVE_BUFRSRC (__has_builtin(__builtin_amdgcn_make_buffer_rsrc) && \
                      __has_builtin(__builtin_amdgcn_raw_buffer_load_f32))

__device__ __forceinline__ float fast_exp2(float x) {
#if __has_builtin(__builtin_amdgcn_exp2f)
    return __builtin_amdgcn_exp2f(x);   // v_exp_f32
#else
    return exp2f(x);
#endif
}

// Stage: byte-compress Z; per-atom float zp table; 94-entry pow table.
__global__ void __launch_bounds__(256) zbl_stage_kernel(
    const int* __restrict__ Z, const float* __restrict__ p,
    unsigned char* __restrict__ z8, float* __restrict__ zpf,
    float* __restrict__ ptab, int n)
{
    int i = blockIdx.x * 256 + threadIdx.x;
    if (i < MAXZ) ptab[i] = powf((float)i, p[0]);   // 0^p = 0, correct
    if (i < n) {
        int z = Z[i];
        z8[i]  = (unsigned char)z;
        zpf[i] = powf((float)z, p[0]);
    }
}

__global__ void __launch_bounds__(BLOCK) zbl_edge_kernel(
    const float*         __restrict__ Dij,
    const int*           __restrict__ idx_i,
    const int*           __restrict__ idx_j,
    const unsigned char* __restrict__ z8,
    const float*         __restrict__ zpf,
    const float*         __restrict__ ptab_g,
    const float*         __restrict__ dptr,
    const float*         __restrict__ c,
    const float*         __restrict__ a,
    float*               __restrict__ out,
    int nAtoms, long long E)
{
    extern __shared__ char smem[];
    unsigned char* s_z8 = (unsigned char*)smem;       // SL bytes
    float*         s_pt = (float*)(smem + SL);        // MAXZ floats

    // Cooperative slice load (ALL threads; barrier before any early-out).
    for (int k = threadIdx.x; k < MAXZ; k += BLOCK) s_pt[k] = ptab_g[k];
    {
        const uint4* src = (const uint4*)z8;          // z8 16B-aligned in ws
        uint4*       dst = (uint4*)s_z8;
        for (int k = threadIdx.x; k < SL / 16; k += BLOCK) dst[k] = src[k];
    }
    __syncthreads();

    const long long t    = (long long)blockIdx.x * BLOCK + threadIdx.x;
    const long long base = t * EPT;
    if (base >= E) return;

    const float LOG2E = 1.4426950408889634f;
    const float invd  = 1.0f / dptr[0];
    const float m0 = -a[0] * LOG2E * invd;
    const float m1 = -a[1] * LOG2E * invd;
    const float m2 = -a[2] * LOG2E * invd;
    const float m3 = -a[3] * LOG2E * invd;
    const float c0 = c[0], c1 = c[1], c2 = c[2], c3 = c[3];

#if HAVE_BUFRSRC
    // SRD over zpf: stride=0, num_records = nAtoms*4 bytes, raw-dword word3.
    // OOB lanes (voffset+4 > num_records) are dropped at the TA: return 0,
    // NO memory request. 0x80000000 can't wrap back in bounds.
    __amdgpu_buffer_rsrc_t srd = __builtin_amdgcn_make_buffer_rsrc(
        (void*)zpf, (short)0, nAtoms * 4, 0x00020000);
#endif

    if (base + EPT <= E) {
        // Phase 1: coalesced streams into registers (12 x dwordx4).
        float dv[EPT];
        int   iv[EPT], jv[EPT];
#pragma unroll
        for (int v = 0; v < EPT; v += 4) {
            const float4 dq = *reinterpret_cast<const float4*>(Dij  + base + v);
            const int4   iq = *reinterpret_cast<const int4*>(idx_i + base + v);
            const int4   jq = *reinterpret_cast<const int4*>(idx_j + base + v);
            dv[v] = dq.x; dv[v+1] = dq.y; dv[v+2] = dq.z; dv[v+3] = dq.w;
            iv[v] = iq.x; iv[v+1] = iq.y; iv[v+2] = iq.z; iv[v+3] = iq.w;
            jv[v] = jq.x; jv[v+1] = jq.y; jv[v+2] = jq.z; jv[v+3] = jq.w;
        }
        // Phase 2a: 16 unconditional buffer_loads; in-slice lanes get an OOB
        // voffset -> dropped at the TA (no miss-path cost). MLP = 16.
        float zg[EPT];
#pragma unroll
        for (int k = 0; k < EPT; ++k) {
#if HAVE_BUFRSRC
            const int voff = (jv[k] < SL) ? (int)0x80000000 : (jv[k] * 4);
            zg[k] = __builtin_amdgcn_raw_buffer_load_f32(srd, voff, 0, 1 /*sc0*/);
#else
            const int jgl = (jv[k] < SL) ? 0 : jv[k];
            zg[k] = __hip_atomic_load(zpf + jgl, __ATOMIC_RELAXED,
                                      __HIP_MEMORY_SCOPE_AGENT);
#endif
        }
        // Phase 2b: 16 LDS lookups, out-of-slice lanes clamped (ds ~free).
        float zl[EPT];
#pragma unroll
        for (int k = 0; k < EPT; ++k) {
            const int jll = (jv[k] < SL) ? jv[k] : 0;          // v_cndmask
            zl[k] = s_pt[s_z8[jll]];
        }
        // Phase 2c: i-side — sorted; endpoint dedup (proven ~free).
        const int   iFirst  = iv[0], iLast = iv[EPT - 1];
        const float zpFirst = zpf[iFirst];
        const float zpLast  = (iLast == iFirst) ? zpFirst : zpf[iLast];
        float zpi[EPT];
#pragma unroll
        for (int k = 0; k < EPT; ++k) {
            zpi[k] = (iv[k] == iFirst) ? zpFirst
                   : (iv[k] == iLast)  ? zpLast
                   : zpf[iv[k]];
        }
        // Phase 3: select + compute + segmented accumulate (idx_i sorted).
        int   cur = iFirst;
        float acc = 0.0f;
#pragma unroll
        for (int k = 0; k < EPT; ++k) {
            const float zpj = (jv[k] < SL) ? zl[k] : zg[k];    // v_cndmask
            const float tt  = dv[k] * (zpi[k] + zpj);
            float v;
            v = c0 * fast_exp2(m0 * tt);
            v = fmaf(c1, fast_exp2(m1 * tt), v);
            v = fmaf(c2, fast_exp2(m2 * tt), v);
            v = fmaf(c3, fast_exp2(m3 * tt), v);
            if (iv[k] != cur) { atomicAdd(out + cur, acc); acc = 0.0f; cur = iv[k]; }
            acc += v;
        }
        atomicAdd(out + cur, acc);
    } else {
        int   cur = idx_i[base];
        float acc = 0.0f;
        for (long long e = base; e < E; ++e) {
            const int   i  = idx_i[e];
            const int   j  = idx_j[e];
            const float zj = (j < SL) ? s_pt[s_z8[j]]
                                      : __hip_atomic_load(zpf + j, __ATOMIC_RELAXED,
                                                          __HIP_MEMORY_SCOPE_AGENT);
            const float tt = Dij[e] * (zpf[i] + zj);
            float v;
            v = c0 * fast_exp2(m0 * tt);
            v = fmaf(c1, fast_exp2(m1 * tt), v);
            v = fmaf(c2, fast_exp2(m2 * tt), v);
            v = fmaf(c3, fast_exp2(m3 * tt), v);
            if (i != cur) { atomicAdd(out + cur, acc); acc = 0.0f; cur = i; }
            acc += v;
        }
        atomicAdd(out + cur, acc);
    }
}

extern "C" void kernel_launch(void* const* d_in, const int* in_sizes, int n_in,
                              void* d_out, int out_size, void* d_ws, size_t ws_size,
                              hipStream_t stream)
{
    const int*   Z     = (const int*)  d_in[0];
    const float* Dij   = (const float*)d_in[1];
    const int*   idx_i = (const int*)  d_in[2];
    const int*   idx_j = (const int*)  d_in[3];
    const float* p     = (const float*)d_in[4];
    const float* d     = (const float*)d_in[5];
    const float* c     = (const float*)d_in[6];
    const float* a     = (const float*)d_in[7];
    float*       out   = (float*)d_out;

    const int       nAtoms = in_sizes[0];
    const long long E      = in_sizes[1];

    // ws layout: [zpf: nAtoms floats][z8: nAtoms bytes, 16B-aligned][ptab].
    float*         zpf   = (float*)d_ws;
    size_t         zoff  = ((size_t)nAtoms * sizeof(float) + 15) & ~(size_t)15;
    unsigned char* z8    = (unsigned char*)d_ws + zoff;
    size_t         poff  = (zoff + (size_t)nAtoms + 63) & ~(size_t)63;
    float*         ptab  = (float*)((char*)d_ws + poff);

    // d_out is re-poisoned 0xAA before every timed launch; we need zeros.
    (void)hipMemsetAsync(d_out, 0, (size_t)out_size * sizeof(float), stream);

    zbl_stage_kernel<<<(nAtoms + 255) / 256, 256, 0, stream>>>(
        Z, p, z8, zpf, ptab, nAtoms);

    const int dynLds = SL + MAXZ * (int)sizeof(float);
    (void)hipFuncSetAttribute((const void*)zbl_edge_kernel,
                              hipFuncAttributeMaxDynamicSharedMemorySize, dynLds);

    const long long nThreads = (E + EPT - 1) / EPT;
    const int       nBlocks  = (int)((nThreads + BLOCK - 1) / BLOCK);
    zbl_edge_kernel<<<nBlocks, BLOCK, dynLds, stream>>>(
        Dij, idx_i, idx_j, z8, zpf, ptab, d, c, a, out, nAtoms, E);
}

// Round 10
// 256.810 us; speedup vs baseline: 1.0470x; 1.0470x over previous
//
#include <hip/hip_runtime.h>

// ZBL screened repulsion + sorted segment sum.
//   d_in[0] Z int32[500000], d_in[1] Dij fp32[16e6], d_in[2] idx_i int32[16e6] (sorted),
//   d_in[3] idx_j int32[16e6], d_in[4] p, d_in[5] d, d_in[6] c[4], d_in[7] a[4]
// Output: fp32[500000] segment_sum over idx_i.
//
// FINAL (revert to round-5 best, 257.8us total / ~121us edge kernel).
// Established cost model (rounds 2-9): divergent-gather cost ~4.6 cyc per
// active lane through the TCP miss-class path, invariant to occupancy, cache
// level (cached vs sc0), payload width, address dedup, and lane masking
// (branchy or OOB-buffer). L1-hit lanes are free. Structural floor:
// 16M random j-lanes x 4.6 cyc / 256 CU / 2.4 GHz = 120us == measured.
// Multi-pass LDS-slice and on-device bucketing designs re-derive the same
// ~120us as pure HBM streaming cost; per-atom state (94 symbols x 500K) is
// incompressible below ~440KB so no L1-resident representation exists.
//
// Structure: per-edge j-gather bypasses L1 (sc0 -> L2-direct float zp);
// i-side served by sorted byte-gather (L1 hits, free) + 94-entry LDS pow
// table; EPT=16 register-batched streams preserve MLP=16 on the gathers;
// segment sum exploits sorted idx_i with ~2 atomics/thread.

#define EPT   16        // edges per thread (16e6 divisible by 16)
#define BLOCK 256
#define MAXZ  95

__device__ __forceinline__ float fast_exp2(float x) {
#if __has_builtin(__builtin_amdgcn_exp2f)
    return __builtin_amdgcn_exp2f(x);   // v_exp_f32
#else
    return exp2f(x);
#endif
}

// Stage: byte-compress Z, build per-atom float zp table and 94-entry pow table.
__global__ void __launch_bounds__(BLOCK) zbl_stage_kernel(
    const int* __restrict__ Z, const float* __restrict__ p,
    unsigned char* __restrict__ z8, float* __restrict__ zpf,
    float* __restrict__ ptab, int n)
{
    int i = blockIdx.x * BLOCK + threadIdx.x;
    if (i < MAXZ) ptab[i] = powf((float)i, p[0]);   // 0^p = 0, correct
    if (i < n) {
        int z = Z[i];
        z8[i]  = (unsigned char)z;
        zpf[i] = powf((float)z, p[0]);
    }
}

__global__ void __launch_bounds__(BLOCK) zbl_edge_kernel(
    const float*         __restrict__ Dij,
    const int*           __restrict__ idx_i,
    const int*           __restrict__ idx_j,
    const unsigned char* __restrict__ z8,
    const float*         __restrict__ zpf,
    const float*         __restrict__ ptab_g,
    const float*         __restrict__ dptr,
    const float*         __restrict__ c,
    const float*         __restrict__ a,
    float*               __restrict__ out,
    long long E)
{
    __shared__ float pt[MAXZ + 1];
    for (int k = threadIdx.x; k < MAXZ; k += BLOCK) pt[k] = ptab_g[k];
    __syncthreads();

    const long long t    = (long long)blockIdx.x * BLOCK + threadIdx.x;
    const long long base = t * EPT;
    if (base >= E) return;

    const float LOG2E = 1.4426950408889634f;
    const float invd  = 1.0f / dptr[0];
    const float m0 = -a[0] * LOG2E * invd;
    const float m1 = -a[1] * LOG2E * invd;
    const float m2 = -a[2] * LOG2E * invd;
    const float m3 = -a[3] * LOG2E * invd;
    const float c0 = c[0], c1 = c[1], c2 = c[2], c3 = c[3];

    if (base + EPT <= E) {
        // Phase 1: coalesced streams into registers (12 x dwordx4).
        float dv[EPT];
        int   iv[EPT], jv[EPT];
#pragma unroll
        for (int v = 0; v < EPT; v += 4) {
            const float4 dq = *reinterpret_cast<const float4*>(Dij  + base + v);
            const int4   iq = *reinterpret_cast<const int4*>(idx_i + base + v);
            const int4   jq = *reinterpret_cast<const int4*>(idx_j + base + v);
            dv[v] = dq.x; dv[v+1] = dq.y; dv[v+2] = dq.z; dv[v+3] = dq.w;
            iv[v] = iq.x; iv[v+1] = iq.y; iv[v+2] = iq.z; iv[v+3] = iq.w;
            jv[v] = jq.x; jv[v+1] = jq.y; jv[v+2] = jq.z; jv[v+3] = jq.w;
        }
        // Phase 2a: j-gathers bypass L1 (agent scope => sc0 => L2 direct).
        float zpj[EPT];
#pragma unroll
        for (int k = 0; k < EPT; ++k) {
            zpj[k] = __hip_atomic_load(zpf + jv[k], __ATOMIC_RELAXED,
                                       __HIP_MEMORY_SCOPE_AGENT);
        }
        // Phase 2b: i-gathers stay cached (sorted -> ~1 line/wave, L1 hits).
        int zi[EPT];
#pragma unroll
        for (int k = 0; k < EPT; ++k) zi[k] = z8[iv[k]];

        // Phase 3: compute + segmented accumulate (idx_i sorted).
        int   cur = iv[0];
        float acc = 0.0f;
#pragma unroll
        for (int k = 0; k < EPT; ++k) {
            const float tt = dv[k] * (pt[zi[k]] + zpj[k]);
            float v;
            v = c0 * fast_exp2(m0 * tt);
            v = fmaf(c1, fast_exp2(m1 * tt), v);
            v = fmaf(c2, fast_exp2(m2 * tt), v);
            v = fmaf(c3, fast_exp2(m3 * tt), v);
            if (iv[k] != cur) { atomicAdd(out + cur, acc); acc = 0.0f; cur = iv[k]; }
            acc += v;
        }
        atomicAdd(out + cur, acc);
    } else {
        int   cur = idx_i[base];
        float acc = 0.0f;
        for (long long e = base; e < E; ++e) {
            const int   i  = idx_i[e];
            const float zj = __hip_atomic_load(zpf + idx_j[e], __ATOMIC_RELAXED,
                                               __HIP_MEMORY_SCOPE_AGENT);
            const float tt = Dij[e] * (pt[z8[i]] + zj);
            float v;
            v = c0 * fast_exp2(m0 * tt);
            v = fmaf(c1, fast_exp2(m1 * tt), v);
            v = fmaf(c2, fast_exp2(m2 * tt), v);
            v = fmaf(c3, fast_exp2(m3 * tt), v);
            if (i != cur) { atomicAdd(out + cur, acc); acc = 0.0f; cur = i; }
            acc += v;
        }
        atomicAdd(out + cur, acc);
    }
}

extern "C" void kernel_launch(void* const* d_in, const int* in_sizes, int n_in,
                              void* d_out, int out_size, void* d_ws, size_t ws_size,
                              hipStream_t stream)
{
    const int*   Z     = (const int*)  d_in[0];
    const float* Dij   = (const float*)d_in[1];
    const int*   idx_i = (const int*)  d_in[2];
    const int*   idx_j = (const int*)  d_in[3];
    const float* p     = (const float*)d_in[4];
    const float* d     = (const float*)d_in[5];
    const float* c     = (const float*)d_in[6];
    const float* a     = (const float*)d_in[7];
    float*       out   = (float*)d_out;

    const int       nAtoms = in_sizes[0];
    const long long E      = in_sizes[1];

    // ws layout: [zpf: nAtoms floats][z8: nAtoms bytes][pad][ptab: MAXZ floats]
    float*         zpf  = (float*)d_ws;
    unsigned char* z8   = (unsigned char*)d_ws + (size_t)nAtoms * sizeof(float);
    size_t         poff = ((size_t)nAtoms * sizeof(float) + (size_t)nAtoms + 63) & ~(size_t)63;
    float*         ptab = (float*)((char*)d_ws + poff);

    // d_out is re-poisoned 0xAA before every timed launch; we need zeros.
    (void)hipMemsetAsync(d_out, 0, (size_t)out_size * sizeof(float), stream);

    zbl_stage_kernel<<<(nAtoms + BLOCK - 1) / BLOCK, BLOCK, 0, stream>>>(
        Z, p, z8, zpf, ptab, nAtoms);

    const long long nThreads = (E + EPT - 1) / EPT;
    const int       nBlocks  = (int)((nThreads + BLOCK - 1) / BLOCK);
    zbl_edge_kernel<<<nBlocks, BLOCK, 0, stream>>>(
        Dij, idx_i, idx_j, z8, zpf, ptab, d, c, a, out, E);
}